// Round 1
// baseline (786.054 us; speedup 1.0000x reference)
//
#include <hip/hip_runtime.h>
#include <hip/hip_bf16.h>

// TGAT fused forward on MI355X (gfx950).
// Shapes: B=4096, N=64, D=De=Dt=128, M=384, H=2, DK=192.
// Structure: prep (weights->bf16) -> qproj (batched MFMA) -> mega (per-b fused
// KV-GEMM + attention) -> tail (batched Wo+LN+MLP MFMA).

typedef __attribute__((ext_vector_type(8))) short bf16x8_t;   // 8 bf16 in 4 VGPRs
typedef __attribute__((ext_vector_type(4))) float f32x4_t;    // MFMA accumulator

__device__ __forceinline__ float bf2f(unsigned short s) {
  union { unsigned u; float f; } v; v.u = ((unsigned)s) << 16; return v.f;
}
__device__ __forceinline__ unsigned short f2bf(float f) {
  union { float f; unsigned u; } v; v.f = f;
  return (unsigned short)((v.u + 0x7fffu + ((v.u >> 16) & 1u)) >> 16);  // RNE
}

// ---------------------------------------------------------------------------
// Kernel 1: convert weights to bf16 layouts in workspace.
//  wq_e [384][256]: Wq cols {0..127, 256..383} (q0's middle 128 cols are zero)
//  wkv  [768][384]: rows 0-383 = Wk, rows 384-767 = Wv
//  wo_b [384][384], w1_b [128][512], w2_b [128][128]: direct copies
// ---------------------------------------------------------------------------
__global__ __launch_bounds__(256) void prep_kernel(
    const float* __restrict__ Wq, const float* __restrict__ Wk,
    const float* __restrict__ Wv, const float* __restrict__ Wo,
    const float* __restrict__ W1, const float* __restrict__ W2,
    unsigned short* __restrict__ wq_e, unsigned short* __restrict__ wkv,
    unsigned short* __restrict__ wo_b, unsigned short* __restrict__ w1_b,
    unsigned short* __restrict__ w2_b) {
  int i = blockIdx.x * 256 + threadIdx.x;
  if (i < 98304) {                                   // 384*256
    int j = i >> 8, kk = i & 255;
    wq_e[i] = f2bf(Wq[j * 384 + (kk < 128 ? kk : kk + 128)]);
  } else if (i < 98304 + 294912) {                   // 768*384
    int idx = i - 98304; int j = idx / 384, m = idx - j * 384;
    wkv[idx] = f2bf(j < 384 ? Wk[j * 384 + m] : Wv[(j - 384) * 384 + m]);
  } else if (i < 98304 + 294912 + 147456) {          // 384*384
    int idx = i - (98304 + 294912);
    wo_b[idx] = f2bf(Wo[idx]);
  } else if (i < 98304 + 294912 + 147456 + 65536) {  // 128*512
    int idx = i - (98304 + 294912 + 147456);
    w1_b[idx] = f2bf(W1[idx]);
  } else if (i < 98304 + 294912 + 147456 + 65536 + 16384) {  // 128*128
    int idx = i - (98304 + 294912 + 147456 + 65536);
    w2_b[idx] = f2bf(W2[idx]);
  }
}

// ---------------------------------------------------------------------------
// Kernel 2: q projection. q_ws[b][j] = sum_m q0[b,m] * Wq[j,m], effective K=256.
// 64 blocks x 256 thr; each block does a (64 x 384 x 256) bf16 MFMA GEMM.
// ---------------------------------------------------------------------------
__global__ __launch_bounds__(256) void qproj_kernel(
    const float* __restrict__ src, const float* __restrict__ srct,
    const unsigned short* __restrict__ wq_e, float* __restrict__ q_ws) {
  __shared__ unsigned short A[64][264];  // pitch 264: 132 dwords = 4 mod 32 banks
  int b0 = blockIdx.x * 64;
  int t = threadIdx.x;
  for (int i = t; i < 4096; i += 256) {  // 64 rows * 64 float4-groups
    int r = i >> 6; int c4 = (i & 63) << 2;
    const float* sp = (c4 < 128) ? (src + (size_t)(b0 + r) * 128 + c4)
                                 : (srct + (size_t)(b0 + r) * 128 + (c4 - 128));
    float4 v = *(const float4*)sp;
    A[r][c4 + 0] = f2bf(v.x); A[r][c4 + 1] = f2bf(v.y);
    A[r][c4 + 2] = f2bf(v.z); A[r][c4 + 3] = f2bf(v.w);
  }
  __syncthreads();
  int l = t & 63, w = t >> 6;
  int lr = l & 15, lg = l >> 4;
  int col0 = w * 96;
  f32x4_t acc[4][6] = {};
#pragma unroll
  for (int ks = 0; ks < 8; ++ks) {
    bf16x8_t a[4];
#pragma unroll
    for (int rt = 0; rt < 4; ++rt)
      a[rt] = *(const bf16x8_t*)&A[rt * 16 + lr][ks * 32 + lg * 8];
#pragma unroll
    for (int ct = 0; ct < 6; ++ct) {
      int col = col0 + ct * 16 + lr;
      bf16x8_t bfr = *(const bf16x8_t*)(wq_e + (size_t)col * 256 + ks * 32 + lg * 8);
#pragma unroll
      for (int rt = 0; rt < 4; ++rt)
        acc[rt][ct] = __builtin_amdgcn_mfma_f32_16x16x32_bf16(a[rt], bfr, acc[rt][ct], 0, 0, 0);
    }
  }
#pragma unroll
  for (int rt = 0; rt < 4; ++rt)
#pragma unroll
    for (int ct = 0; ct < 6; ++ct) {
      int col = col0 + ct * 16 + lr;
#pragma unroll
      for (int r = 0; r < 4; ++r) {
        int row = rt * 16 + lg * 4 + r;  // D-frag: row=(lane>>4)*4+reg
        q_ws[(size_t)(b0 + row) * 384 + col] = acc[rt][ct][r];
      }
    }
}

// ---------------------------------------------------------------------------
// Kernel 3: mega. One block per b (4096 blocks, 512 thr = 8 waves).
//  P1: KV = k0 @ [Wk|Wv]^T via MFMA; k0 staged in LDS in 64-col chunks
//      (double-buffered, prefetch overlaps MFMA).
//  P2: KV (fp32 acc) -> bf16 LDS [64][776].
//  P3: scores + softmax (fp32 vector, wave-wide shfl reduce); writes attn_sq.
//  P4: out = attn @ V (fp32 vector); writes attnout_ws (pre-Wo vector).
// Dynamic LDS = 119808 B.
// ---------------------------------------------------------------------------
__global__ __launch_bounds__(512, 2) void mega_kernel(
    const float* __restrict__ seq, const float* __restrict__ seq_e,
    const float* __restrict__ seq_t, const int* __restrict__ mask,
    const unsigned short* __restrict__ wkv, const float* __restrict__ q_ws,
    float* __restrict__ attnout, float* __restrict__ attn_sq) {
  extern __shared__ char smem[];
  unsigned short* k0c = (unsigned short*)smem;            // [2][64][72]  18432 B
  unsigned short* kv  = (unsigned short*)(smem + 18432);  // [64][776]    99328 B
  float* qv     = (float*)(smem + 18432 + 99328);         // [384]
  float* attn_l = qv + 384;                               // [2][64]

  int b = blockIdx.x;
  int t = threadIdx.x;
  int l = t & 63, w = t >> 6;
  int lr = l & 15, lg = l >> 4;

  if (t < 384) qv[t] = q_ws[(size_t)b * 384 + t];

  int ln = t >> 3;           // staging row 0..63
  int lc = (t & 7) << 3;     // staging col-in-chunk 0..56 (8 floats each)
  auto chunk_src = [&](int kc) -> const float* {
    const float* base = (kc < 2) ? seq : (kc < 4 ? seq_e : seq_t);
    int mo = (kc & 1) << 6;
    return base + ((size_t)b * 64 + ln) * 128 + mo + lc;
  };

  {  // prologue: stage chunk 0 into buf 0
    const float* p = chunk_src(0);
    float4 v0 = *(const float4*)p;
    float4 v1 = *(const float4*)(p + 4);
    bf16x8_t t8;
    t8[0] = (short)f2bf(v0.x); t8[1] = (short)f2bf(v0.y);
    t8[2] = (short)f2bf(v0.z); t8[3] = (short)f2bf(v0.w);
    t8[4] = (short)f2bf(v1.x); t8[5] = (short)f2bf(v1.y);
    t8[6] = (short)f2bf(v1.z); t8[7] = (short)f2bf(v1.w);
    *(bf16x8_t*)&k0c[ln * 72 + lc] = t8;
  }
  __syncthreads();

  int col0 = w * 96;  // this wave's 96 output cols of 768 (K: 0-383, V: 384-767)
  f32x4_t acc[4][6] = {};
  int buf = 0;
#pragma unroll
  for (int kc = 0; kc < 6; ++kc) {
    float4 p0, p1;
    if (kc < 5) {  // prefetch next chunk (HBM latency hides under MFMA below)
      const float* p = chunk_src(kc + 1);
      p0 = *(const float4*)p;
      p1 = *(const float4*)(p + 4);
    }
    bf16x8_t a[2][4];
#pragma unroll
    for (int ks = 0; ks < 2; ++ks)
#pragma unroll
      for (int rt = 0; rt < 4; ++rt)
        a[ks][rt] = *(const bf16x8_t*)&k0c[(buf * 64 + rt * 16 + lr) * 72 + ks * 32 + lg * 8];
    bf16x8_t bfrag[6][2];
#pragma unroll
    for (int ct = 0; ct < 6; ++ct)
#pragma unroll
      for (int ks = 0; ks < 2; ++ks)
        bfrag[ct][ks] = *(const bf16x8_t*)(wkv + (size_t)(col0 + ct * 16 + lr) * 384 +
                                           kc * 64 + ks * 32 + lg * 8);
#pragma unroll
    for (int ct = 0; ct < 6; ++ct)
#pragma unroll
      for (int ks = 0; ks < 2; ++ks)
#pragma unroll
        for (int rt = 0; rt < 4; ++rt)
          acc[rt][ct] = __builtin_amdgcn_mfma_f32_16x16x32_bf16(a[ks][rt], bfrag[ct][ks],
                                                                acc[rt][ct], 0, 0, 0);
    if (kc < 5) {
      bf16x8_t t8;
      t8[0] = (short)f2bf(p0.x); t8[1] = (short)f2bf(p0.y);
      t8[2] = (short)f2bf(p0.z); t8[3] = (short)f2bf(p0.w);
      t8[4] = (short)f2bf(p1.x); t8[5] = (short)f2bf(p1.y);
      t8[6] = (short)f2bf(p1.z); t8[7] = (short)f2bf(p1.w);
      *(bf16x8_t*)&k0c[((buf ^ 1) * 64 + ln) * 72 + lc] = t8;
      buf ^= 1;
    }
    __syncthreads();
  }

  // P2: accumulators -> kv LDS (bf16)
#pragma unroll
  for (int rt = 0; rt < 4; ++rt)
#pragma unroll
    for (int ct = 0; ct < 6; ++ct) {
      int col = col0 + ct * 16 + lr;
#pragma unroll
      for (int r = 0; r < 4; ++r)
        kv[(rt * 16 + lg * 4 + r) * 776 + col] = f2bf(acc[rt][ct][r]);
    }
  __syncthreads();

  // P3: scores + softmax. Waves 0,1 <-> heads 0,1; lane = n.
  if (t < 128) {
    int h = w, n = l;
    float s = 0.f;
#pragma unroll
    for (int d0 = 0; d0 < 192; d0 += 8) {
      bf16x8_t kk = *(const bf16x8_t*)&kv[n * 776 + h * 192 + d0];
#pragma unroll
      for (int j = 0; j < 8; ++j) s += bf2f((unsigned short)kk[j]) * qv[h * 192 + d0 + j];
    }
    s *= 0.07216878364870323f;  // 1/sqrt(192)
    if (mask[b * 64 + n] != 0) s = -1e10f;
    float mx = s;
#pragma unroll
    for (int off = 32; off > 0; off >>= 1) mx = fmaxf(mx, __shfl_xor(mx, off, 64));
    float p = __expf(s - mx);
    float sm = p;
#pragma unroll
    for (int off = 32; off > 0; off >>= 1) sm += __shfl_xor(sm, off, 64);
    float a = p / sm;
    attn_l[h * 64 + n] = a;
    attn_sq[((size_t)h * 4096 + b) * 64 + n] = a;  // attn.transpose(1,0,2,3)
  }
  __syncthreads();

  // P4: out[j] = sum_n attn[h][n] * V[n][j],  j = h*192+d
  if (t < 384) {
    int h = (t >= 192);
    float o = 0.f;
#pragma unroll 8
    for (int n = 0; n < 64; ++n) o += attn_l[h * 64 + n] * bf2f(kv[n * 776 + 384 + t]);
    attnout[(size_t)b * 384 + t] = o;
  }
}

// ---------------------------------------------------------------------------
// Kernel 4: tail. 64 blocks x 256 thr; 64 b-rows each.
//  GEMM1 (Wo) -> +bo +q0 -> in-register LN (16-lane shfl + LDS partials)
//  -> X=[ln_out|src] bf16 -> GEMM2 (W1)+relu -> GEMM3 (W2) -> y.
// Dynamic LDS = 69632 B.
// ---------------------------------------------------------------------------
__global__ __launch_bounds__(256) void tail_kernel(
    const float* __restrict__ attnout, const float* __restrict__ src,
    const float* __restrict__ srct,
    const unsigned short* __restrict__ wo_b, const unsigned short* __restrict__ w1_b,
    const unsigned short* __restrict__ w2_b,
    const float* __restrict__ bo, const float* __restrict__ lng,
    const float* __restrict__ lnb, const float* __restrict__ b1,
    const float* __restrict__ b2, float* __restrict__ y) {
  extern __shared__ char smem[];
  unsigned short* R  = (unsigned short*)smem;            // [64][392]: A1 then Xa
  unsigned short* Xs = (unsigned short*)(smem + 50176);  // [64][136]: src bf16, then Hl
  float* psum = (float*)(smem + 50176 + 17408);          // [64][4]
  float* psq  = psum + 256;                              // [64][4]

  int b0 = blockIdx.x * 64;
  int t = threadIdx.x;
  int l = t & 63, w = t >> 6;
  int lr = l & 15, lg = l >> 4;

  // stage attnout -> R (bf16) and src -> Xs (bf16)
  for (int i = t; i < 6144; i += 256) {  // 64*384/4
    int r = i / 96; int c4 = (i - r * 96) << 2;
    float4 v = *(const float4*)(attnout + (size_t)(b0 + r) * 384 + c4);
    R[r * 392 + c4 + 0] = f2bf(v.x); R[r * 392 + c4 + 1] = f2bf(v.y);
    R[r * 392 + c4 + 2] = f2bf(v.z); R[r * 392 + c4 + 3] = f2bf(v.w);
  }
  for (int i = t; i < 2048; i += 256) {  // 64*128/4
    int r = i >> 5; int c4 = (i & 31) << 2;
    float4 v = *(const float4*)(src + (size_t)(b0 + r) * 128 + c4);
    Xs[r * 136 + c4 + 0] = f2bf(v.x); Xs[r * 136 + c4 + 1] = f2bf(v.y);
    Xs[r * 136 + c4 + 2] = f2bf(v.z); Xs[r * 136 + c4 + 3] = f2bf(v.w);
  }
  __syncthreads();

  // GEMM1: out1 = attnout @ Wo^T   (64 x 384 x 384)
  int col0 = w * 96;
  f32x4_t acc[4][6] = {};
#pragma unroll
  for (int ks = 0; ks < 12; ++ks) {
    bf16x8_t a[4];
#pragma unroll
    for (int rt = 0; rt < 4; ++rt)
      a[rt] = *(const bf16x8_t*)&R[(rt * 16 + lr) * 392 + ks * 32 + lg * 8];
#pragma unroll
    for (int ct = 0; ct < 6; ++ct) {
      bf16x8_t bfr = *(const bf16x8_t*)(wo_b + (size_t)(col0 + ct * 16 + lr) * 384 +
                                        ks * 32 + lg * 8);
#pragma unroll
      for (int rt = 0; rt < 4; ++rt)
        acc[rt][ct] = __builtin_amdgcn_mfma_f32_16x16x32_bf16(a[rt], bfr, acc[rt][ct], 0, 0, 0);
    }
  }

  // res = out1 + bo + q0; per-(row) sum/sumsq partials via 16-lane butterfly
  float bov[6];
#pragma unroll
  for (int ct = 0; ct < 6; ++ct) bov[ct] = bo[col0 + ct * 16 + lr];
#pragma unroll
  for (int rt = 0; rt < 4; ++rt)
#pragma unroll
    for (int r = 0; r < 4; ++r) {
      int row = rt * 16 + lg * 4 + r;
      float s = 0.f, ss = 0.f;
#pragma unroll
      for (int ct = 0; ct < 6; ++ct) {
        int col = col0 + ct * 16 + lr;
        float v = acc[rt][ct][r] + bov[ct];
        if (col < 128) v += src[(size_t)(b0 + row) * 128 + col];
        else if (col >= 256) v += srct[(size_t)(b0 + row) * 128 + (col - 256)];
        acc[rt][ct][r] = v;
        s += v; ss += v * v;
      }
#pragma unroll
      for (int off = 1; off < 16; off <<= 1) {
        s += __shfl_xor(s, off, 64);
        ss += __shfl_xor(ss, off, 64);
      }
      if (lr == 0) { psum[row * 4 + w] = s; psq[row * 4 + w] = ss; }
    }
  __syncthreads();  // also: all waves done reading R (A1) -> safe to overwrite

  // LN + write Xa (into R region)
  float gcv[6], bcv[6];
#pragma unroll
  for (int ct = 0; ct < 6; ++ct) {
    gcv[ct] = lng[col0 + ct * 16 + lr];
    bcv[ct] = lnb[col0 + ct * 16 + lr];
  }
#pragma unroll
  for (int rt = 0; rt < 4; ++rt)
#pragma unroll
    for (int r = 0; r < 4; ++r) {
      int row = rt * 16 + lg * 4 + r;
      float s4 = psum[row * 4 + 0] + psum[row * 4 + 1] + psum[row * 4 + 2] + psum[row * 4 + 3];
      float q4 = psq[row * 4 + 0] + psq[row * 4 + 1] + psq[row * 4 + 2] + psq[row * 4 + 3];
      float m = s4 * (1.f / 384.f);
      float var = q4 * (1.f / 384.f) - m * m;
      float rs = rsqrtf(var + 1e-5f);
#pragma unroll
      for (int ct = 0; ct < 6; ++ct) {
        int col = col0 + ct * 16 + lr;
        float v = (acc[rt][ct][r] - m) * rs * gcv[ct] + bcv[ct];
        R[row * 392 + col] = f2bf(v);
      }
    }
  __syncthreads();

  // GEMM2: h = relu(X @ W1^T + b1)   (64 x 128 x 512); X = [Xa(384) | Xs(128)]
  int c20 = w * 32;
  f32x4_t acc2[4][2] = {};
#pragma unroll
  for (int ks = 0; ks < 16; ++ks) {
    bf16x8_t a[4];
#pragma unroll
    for (int rt = 0; rt < 4; ++rt)
      a[rt] = (ks < 12)
        ? *(const bf16x8_t*)&R[(rt * 16 + lr) * 392 + ks * 32 + lg * 8]
        : *(const bf16x8_t*)&Xs[(rt * 16 + lr) * 136 + (ks - 12) * 32 + lg * 8];
#pragma unroll
    for (int ct = 0; ct < 2; ++ct) {
      bf16x8_t bfr = *(const bf16x8_t*)(w1_b + (size_t)(c20 + ct * 16 + lr) * 512 +
                                        ks * 32 + lg * 8);
#pragma unroll
      for (int rt = 0; rt < 4; ++rt)
        acc2[rt][ct] = __builtin_amdgcn_mfma_f32_16x16x32_bf16(a[rt], bfr, acc2[rt][ct], 0, 0, 0);
    }
  }
  __syncthreads();  // all GEMM2 reads of Xs done before Hl overlay
  unsigned short* Hl = Xs;  // [64][136]
#pragma unroll
  for (int ct = 0; ct < 2; ++ct) {
    int col = c20 + ct * 16 + lr;
    float bb = b1[col];
#pragma unroll
    for (int rt = 0; rt < 4; ++rt)
#pragma unroll
      for (int r = 0; r < 4; ++r) {
        int row = rt * 16 + lg * 4 + r;
        Hl[row * 136 + col] = f2bf(fmaxf(acc2[rt][ct][r] + bb, 0.f));
      }
  }
  __syncthreads();

  // GEMM3: y = H @ W2^T + b2   (64 x 128 x 128)
  f32x4_t acc3[4][2] = {};
#pragma unroll
  for (int ks = 0; ks < 4; ++ks) {
    bf16x8_t a[4];
#pragma unroll
    for (int rt = 0; rt < 4; ++rt)
      a[rt] = *(const bf16x8_t*)&Hl[(rt * 16 + lr) * 136 + ks * 32 + lg * 8];
#pragma unroll
    for (int ct = 0; ct < 2; ++ct) {
      bf16x8_t bfr = *(const bf16x8_t*)(w2_b + (size_t)(c20 + ct * 16 + lr) * 128 +
                                        ks * 32 + lg * 8);
#pragma unroll
      for (int rt = 0; rt < 4; ++rt)
        acc3[rt][ct] = __builtin_amdgcn_mfma_f32_16x16x32_bf16(a[rt], bfr, acc3[rt][ct], 0, 0, 0);
    }
  }
#pragma unroll
  for (int ct = 0; ct < 2; ++ct) {
    int col = c20 + ct * 16 + lr;
    float bb = b2[col];
#pragma unroll
    for (int rt = 0; rt < 4; ++rt)
#pragma unroll
      for (int r = 0; r < 4; ++r) {
        int row = rt * 16 + lg * 4 + r;
        y[(size_t)(b0 + row) * 128 + col] = acc3[rt][ct][r] + bb;
      }
  }
}

// ---------------------------------------------------------------------------
extern "C" void kernel_launch(void* const* d_in, const int* in_sizes, int n_in,
                              void* d_out, int out_size, void* d_ws, size_t ws_size,
                              hipStream_t stream) {
  const float* src   = (const float*)d_in[0];
  const float* src_t = (const float*)d_in[1];
  const float* seq   = (const float*)d_in[2];
  const float* seq_t = (const float*)d_in[3];
  const float* seq_e = (const float*)d_in[4];
  const int*   mask  = (const int*)d_in[5];
  const float* Wq = (const float*)d_in[6];
  const float* Wk = (const float*)d_in[7];
  const float* Wv = (const float*)d_in[8];
  const float* Wo = (const float*)d_in[9];
  const float* bo = (const float*)d_in[10];
  const float* ln_g = (const float*)d_in[11];
  const float* ln_b = (const float*)d_in[12];
  const float* W1 = (const float*)d_in[13];
  const float* b1 = (const float*)d_in[14];
  const float* W2 = (const float*)d_in[15];
  const float* b2 = (const float*)d_in[16];

  float* y_out    = (float*)d_out;        // [4096][128]
  float* attn_out = y_out + 4096 * 128;   // [8192][64]

  char* ws = (char*)d_ws;
  unsigned short* wq_e = (unsigned short*)ws;  ws += 98304 * 2;
  unsigned short* wkv  = (unsigned short*)ws;  ws += 294912 * 2;
  unsigned short* wo_b = (unsigned short*)ws;  ws += 147456 * 2;
  unsigned short* w1_b = (unsigned short*)ws;  ws += 65536 * 2;
  unsigned short* w2_b = (unsigned short*)ws;  ws += 16384 * 2;
  float* q_ws    = (float*)ws;                 ws += (size_t)4096 * 384 * 4;
  float* attnout = (float*)ws;                 ws += (size_t)4096 * 384 * 4;

  hipFuncSetAttribute((const void*)mega_kernel,
                      hipFuncAttributeMaxDynamicSharedMemorySize, 119808);
  hipFuncSetAttribute((const void*)tail_kernel,
                      hipFuncAttributeMaxDynamicSharedMemorySize, 69632);

  prep_kernel<<<dim3(2432), dim3(256), 0, stream>>>(Wq, Wk, Wv, Wo, W1, W2,
                                                    wq_e, wkv, wo_b, w1_b, w2_b);
  qproj_kernel<<<dim3(64), dim3(256), 0, stream>>>(src, src_t, wq_e, q_ws);
  mega_kernel<<<dim3(4096), dim3(512), 119808, stream>>>(seq, seq_e, seq_t, mask,
                                                         wkv, q_ws, attnout, attn_out);
  tail_kernel<<<dim3(64), dim3(256), 69632, stream>>>(attnout, src, src_t,
                                                      wo_b, w1_b, w2_b,
                                                      bo, ln_g, ln_b, b1, b2, y_out);
}